// Round 10
// baseline (183.023 us; speedup 1.0000x reference)
//
#include <hip/hip_runtime.h>
#include <stdint.h>

typedef unsigned short u16;
typedef __bf16 bf16x8 __attribute__((ext_vector_type(8)));
typedef float f32x4 __attribute__((ext_vector_type(4)));
typedef __attribute__((address_space(3))) void as3_void;
typedef __attribute__((address_space(1))) void as1_void;

#define NU   1024
#define NBB  8192

// Degree-4 constrained-Chebyshev init for 1/lambda on [2, 13.8]:
// X0 = C0*I + C1*M + M^2*(C2*I + C3*M + C4*M^2), e0 = 0.0363
#define C0 0.9513167f
#define C1 (-0.3169175f)
#define C2 0.0471891f
#define C3 (-0.00321059f)
#define C4 0.00008127825f

// ---------- bf16 helpers (RNE, bit ops; inputs finite) ----------
__device__ __forceinline__ u16 f2h(float f) {
  union { float f; uint32_t u; } c; c.f = f;
  uint32_t r = (c.u + 0x7fffu + ((c.u >> 16) & 1u)) >> 16;
  return (u16)r;
}
__device__ __forceinline__ float h2f(u16 h) {
  union { uint32_t u; float f; } c; c.u = ((uint32_t)h) << 16;
  return c.f;
}

__device__ __forceinline__ void gload16(const u16* g, u16* l) {
  __builtin_amdgcn_global_load_lds((const as1_void*)g, (as3_void*)l, 16, 0, 0);
}

// ---------- prep: B0 -> bf16 B0h (plain hi), B0Th/B0Tl (transposed hi/lo) ----------
__global__ void prep_b0(const float* __restrict__ B0, u16* __restrict__ B0h,
                        u16* __restrict__ B0Th, u16* __restrict__ B0Tl) {
  __shared__ float t[32][33];
  const int bx = blockIdx.x, by = blockIdx.y;
  const int x = threadIdx.x, y0 = threadIdx.y;
  #pragma unroll
  for (int yy = y0; yy < 32; yy += 8) {
    const int r = by * 32 + yy, c = bx * 32 + x;
    const float v = B0[(size_t)r * NU + c];
    t[yy][x] = v;
    B0h[(size_t)r * NU + c] = f2h(v);
  }
  __syncthreads();
  #pragma unroll
  for (int yy = y0; yy < 32; yy += 8) {
    const int r = bx * 32 + yy, c = by * 32 + x;  // B0T[r][c] = B0[c][r]
    const float v = t[x][yy];
    const u16 hh = f2h(v);
    B0Th[(size_t)r * NU + c] = hh;
    B0Tl[(size_t)r * NU + c] = f2h(v - h2f(hh));
  }
}

// ---------- z1T[b][i] = bf16(v0[i][b]+0.1q[i]); z2T[b][i] = bf16(v1[i][b]+tanh(v0[i][b])) ----------
__global__ void build_zT(const float* __restrict__ v0, const float* __restrict__ v1,
                         const float* __restrict__ q,
                         u16* __restrict__ z1T, u16* __restrict__ z2T) {
  __shared__ u16 s1[32][33], s2[32][33];
  const int bx = blockIdx.x;  // batch tile
  const int by = blockIdx.y;  // unit tile
  const int x = threadIdx.x, y0 = threadIdx.y;
  #pragma unroll
  for (int yy = y0; yy < 32; yy += 8) {
    const int i = by * 32 + yy;
    const int b = bx * 32 + x;
    const float a0 = v0[(size_t)i * NBB + b];
    const float a1 = v1[(size_t)i * NBB + b];
    s1[yy][x] = f2h(a0 + 0.1f * q[i]);
    s2[yy][x] = f2h(a1 + tanhf(a0));
  }
  __syncthreads();
  #pragma unroll
  for (int yy = y0; yy < 32; yy += 8) {
    const int b = bx * 32 + yy;
    const int i = by * 32 + x;
    z1T[(size_t)b * NU + i] = s1[x][yy];
    z2T[(size_t)b * NU + i] = s2[x][yy];
  }
}

// ---------- G = C2*I + C3*M + C4*M2 (elementwise, bf16) ----------
__global__ void build_g(const u16* __restrict__ Mh, const u16* __restrict__ M2,
                        u16* __restrict__ G) {
  const int idx = blockIdx.x * 256 + threadIdx.x;
  const int i = idx >> 10, j = idx & 1023;
  const float v = C3 * h2f(Mh[idx]) + C4 * h2f(M2[idx]) + ((i == j) ? C2 : 0.f);
  G[idx] = f2h(v);
}

// ---------- small setup GEMM: 64x64 tile, BK=128, 4 waves, PDIST-deep
// prefetch, issue-early staging, counted vmcnt. C = A * Bt^T, 1024^3.
// NOPS: 2 = A0*B0; 3 = (A0+A1)*B0; 4 = A0B0 + A1B0 + A0B1 (split precision).
// Epilogue: v = alpha*acc + beta*aux + gamma*I -> outH (+outL lo part). ----------
template<int NOPS, int PDIST>
__global__ __launch_bounds__(256, 1)
void gemm_s(const u16* __restrict__ A0, const u16* __restrict__ A1,
            const u16* __restrict__ Bt0, const u16* __restrict__ Bt1,
            int lda, int ldb,
            const u16* __restrict__ aux, int ldaux,
            float alpha, float beta, float gamma,
            u16* __restrict__ outH, u16* __restrict__ outL, int ldc) {
  constexpr int BK = 128;          // K-step
  constexpr int NA = (NOPS >= 3) ? 2 : 1;
  constexpr int NB2 = (NOPS == 4) ? 2 : 1;
  constexpr int RA = 4;            // 64*128 elems / (256 thr * 8 elems)
  constexpr int LOADS = RA * (NA + NB2);
  __shared__ u16 Al[PDIST][NA][64 * BK];
  __shared__ u16 Bl[PDIST][NB2][64 * BK];

  int wg = (int)blockIdx.x;
  { wg = (wg & 7) * 32 + (wg >> 3); }  // XCD swizzle, grid 256
  const int tm = wg & 15, tn = wg >> 4;
  const int row0 = tm << 6, col0 = tn << 6;

  const int tid = threadIdx.x;
  const int lane = tid & 63, wid = tid >> 6;
  const int wm = wid >> 1, wn = wid & 1;
  const int r16 = lane & 15, ch = lane >> 4;

  f32x4 acc[2][2] = {};

  auto stageAll = [&](int k0, int buf) {
    #pragma unroll
    for (int h = 0; h < RA; ++h) {
      const int L = tid + (h << 8);
      const int row = L >> 4;                 // 16 segs of 8 elems per row
      const int ss = (L & 15) ^ (row & 7);
      const size_t go = (size_t)(row0 + row) * lda + (size_t)(k0 + (ss << 3));
      gload16(A0 + go, &Al[buf][0][(L & ~63) << 3]);
      if constexpr (NA == 2) gload16(A1 + go, &Al[buf][1][(L & ~63) << 3]);
    }
    #pragma unroll
    for (int h = 0; h < RA; ++h) {
      const int L = tid + (h << 8);
      const int row = L >> 4;
      const int ss = (L & 15) ^ (row & 7);
      const size_t go = (size_t)(col0 + row) * ldb + (size_t)(k0 + (ss << 3));
      gload16(Bt0 + go, &Bl[buf][0][(L & ~63) << 3]);
      if constexpr (NB2 == 2) gload16(Bt1 + go, &Bl[buf][1][(L & ~63) << 3]);
    }
  };

  const int nK = 1024 / BK;  // 8
  stageAll(0, 0);
  if constexpr (PDIST == 3) stageAll(BK, 1);

  int cur = 0;
  for (int t = 0; t < nK; ++t) {
    int bs = cur + (PDIST - 1); if (bs >= PDIST) bs -= PDIST;
    if (t + PDIST - 1 < nK) {
      stageAll((t + PDIST - 1) * BK, bs);
      if constexpr (PDIST == 2) {
        if constexpr (LOADS == 8)  asm volatile("s_waitcnt vmcnt(8)" ::: "memory");
        else if constexpr (LOADS == 12) asm volatile("s_waitcnt vmcnt(12)" ::: "memory");
        else asm volatile("s_waitcnt vmcnt(16)" ::: "memory");
      } else {
        if constexpr (LOADS == 8)  asm volatile("s_waitcnt vmcnt(16)" ::: "memory");
        else asm volatile("s_waitcnt vmcnt(24)" ::: "memory");
      }
    } else if (PDIST == 3 && t + 1 < nK) {
      if constexpr (LOADS == 8)  asm volatile("s_waitcnt vmcnt(8)" ::: "memory");
      else asm volatile("s_waitcnt vmcnt(12)" ::: "memory");
    } else {
      asm volatile("s_waitcnt vmcnt(0)" ::: "memory");
    }
    __builtin_amdgcn_sched_barrier(0);
    __builtin_amdgcn_s_barrier();
    __builtin_amdgcn_sched_barrier(0);

    #pragma unroll
    for (int kk = 0; kk < BK / 32; ++kk) {
      bf16x8 av[2], bv[2], av1[2], bv1[2];
      #pragma unroll
      for (int f = 0; f < 2; ++f) {
        const int ra = (wm << 5) + (f << 4) + r16;
        const int sa = ((kk << 2) + ch) ^ (ra & 7);
        av[f] = *(const bf16x8*)&Al[cur][0][ra * BK + (sa << 3)];
        if constexpr (NA == 2)
          av1[f] = *(const bf16x8*)&Al[cur][1][ra * BK + (sa << 3)];
        const int rb = (wn << 5) + (f << 4) + r16;
        const int sb = ((kk << 2) + ch) ^ (rb & 7);
        bv[f] = *(const bf16x8*)&Bl[cur][0][rb * BK + (sb << 3)];
        if constexpr (NB2 == 2)
          bv1[f] = *(const bf16x8*)&Bl[cur][1][rb * BK + (sb << 3)];
      }
      __builtin_amdgcn_s_setprio(1);
      #pragma unroll
      for (int fm = 0; fm < 2; ++fm)
        #pragma unroll
        for (int fn = 0; fn < 2; ++fn)
          acc[fm][fn] = __builtin_amdgcn_mfma_f32_16x16x32_bf16(av[fm], bv[fn], acc[fm][fn], 0, 0, 0);
      if constexpr (NA == 2) {
        #pragma unroll
        for (int fm = 0; fm < 2; ++fm)
          #pragma unroll
          for (int fn = 0; fn < 2; ++fn)
            acc[fm][fn] = __builtin_amdgcn_mfma_f32_16x16x32_bf16(av1[fm], bv[fn], acc[fm][fn], 0, 0, 0);
      }
      if constexpr (NB2 == 2) {
        #pragma unroll
        for (int fm = 0; fm < 2; ++fm)
          #pragma unroll
          for (int fn = 0; fn < 2; ++fn)
            acc[fm][fn] = __builtin_amdgcn_mfma_f32_16x16x32_bf16(av[fm], bv1[fn], acc[fm][fn], 0, 0, 0);
      }
      __builtin_amdgcn_s_setprio(0);
    }
    __builtin_amdgcn_sched_barrier(0);
    __builtin_amdgcn_s_barrier();
    __builtin_amdgcn_sched_barrier(0);
    ++cur; if (cur == PDIST) cur = 0;
  }

  // epilogue: C/D layout: col = lane&15, row = (lane>>4)*4 + j
  const int rbase = row0 + (wm << 5) + ((lane >> 4) << 2);
  const int cbase = col0 + (wn << 5) + (lane & 15);
  #pragma unroll
  for (int fm = 0; fm < 2; ++fm)
    #pragma unroll
    for (int fn = 0; fn < 2; ++fn)
      #pragma unroll
      for (int j = 0; j < 4; ++j) {
        const int gr = rbase + (fm << 4) + j;
        const int gc = cbase + (fn << 4);
        float v = alpha * acc[fm][fn][j];
        if (aux) v += beta * h2f(aux[(size_t)gr * ldaux + gc]);
        if (gamma != 0.f && gr == gc) v += gamma;
        const u16 hh = f2h(v);
        outH[(size_t)gr * ldc + gc] = hh;
        if (outL) outL[(size_t)gr * ldc + gc] = f2h(v - h2f(hh));
      }
}

// ---------- apply stage A (m97-class): 128x128 tile, BK=64, 4 waves (2x2),
// wave tile 64x64, dbuf LDS, counted vmcnt(8), 2 blocks/CU.
// outH = bf16(A*Bt^T + aux)  [t1T = z1T*B0 + z2T] ----------
__global__ __launch_bounds__(256, 2)
void gemm_a(const u16* __restrict__ A, const u16* __restrict__ Bt,
            const u16* __restrict__ aux, u16* __restrict__ outH,
            int lda, int ldb, int ldc, int M, int N, int K) {
  __shared__ u16 Al[2][128 * 64];  // 16 KB each
  __shared__ u16 Bl[2][128 * 64];  // total 64 KB

  const int nTm = M >> 7, nTn = N >> 7;
  const int nwg = nTm * nTn;
  int wg = (int)blockIdx.x;
  { const int c = nwg >> 3; wg = (wg & 7) * c + (wg >> 3); }  // XCD swizzle
  const int tm = wg % nTm, tn = wg / nTm;                     // tn-major
  const int row0 = tm << 7, col0 = tn << 7;

  const int tid = threadIdx.x;
  const int lane = tid & 63, wid = tid >> 6;
  const int wm = wid >> 1, wn = wid & 1;
  const int r16 = lane & 15, ch = lane >> 4;

  f32x4 acc[4][4] = {};

  auto stage = [&](const u16* __restrict__ G, int gld, int grow0, int k0, u16* lb) {
    #pragma unroll
    for (int h = 0; h < 4; ++h) {
      const int L = tid + (h << 8);
      const int row = L >> 3, seg = L & 7;
      const int ss = seg ^ (row & 7);
      gload16(G + (size_t)(grow0 + row) * gld + (size_t)(k0 + (ss << 3)),
              lb + ((L & ~63) << 3));
    }
  };

  const int nK = K >> 6;
  stage(A, lda, row0, 0, &Al[0][0]);
  stage(Bt, ldb, col0, 0, &Bl[0][0]);

  for (int t = 0; t < nK; ++t) {
    const int cur = t & 1;
    if (t + 1 < nK) {
      stage(A, lda, row0, (t + 1) << 6, &Al[cur ^ 1][0]);
      stage(Bt, ldb, col0, (t + 1) << 6, &Bl[cur ^ 1][0]);
      asm volatile("s_waitcnt vmcnt(8)" ::: "memory");
    } else {
      asm volatile("s_waitcnt vmcnt(0)" ::: "memory");
    }
    __builtin_amdgcn_sched_barrier(0);
    __builtin_amdgcn_s_barrier();
    __builtin_amdgcn_sched_barrier(0);

    #pragma unroll
    for (int kk = 0; kk < 2; ++kk) {
      bf16x8 av[4], bv[4];
      #pragma unroll
      for (int f = 0; f < 4; ++f) {
        const int ra = (wm << 6) + (f << 4) + r16;
        const int sa = ((kk << 2) + ch) ^ (ra & 7);
        av[f] = *(const bf16x8*)&Al[cur][(ra << 6) + (sa << 3)];
        const int rb = (wn << 6) + (f << 4) + r16;
        const int sb = ((kk << 2) + ch) ^ (rb & 7);
        bv[f] = *(const bf16x8*)&Bl[cur][(rb << 6) + (sb << 3)];
      }
      __builtin_amdgcn_s_setprio(1);
      #pragma unroll
      for (int fm = 0; fm < 4; ++fm)
        #pragma unroll
        for (int fn = 0; fn < 4; ++fn)
          acc[fm][fn] = __builtin_amdgcn_mfma_f32_16x16x32_bf16(av[fm], bv[fn], acc[fm][fn], 0, 0, 0);
      __builtin_amdgcn_s_setprio(0);
    }
    __builtin_amdgcn_sched_barrier(0);
    __builtin_amdgcn_s_barrier();
    __builtin_amdgcn_sched_barrier(0);
  }

  const int rbase = row0 + (wm << 6) + ((lane >> 4) << 2);
  const int cbase = col0 + (wn << 6) + (lane & 15);
  #pragma unroll
  for (int fm = 0; fm < 4; ++fm)
    #pragma unroll
    for (int fn = 0; fn < 4; ++fn)
      #pragma unroll
      for (int j = 0; j < 4; ++j) {
        const int gr = rbase + (fm << 4) + j;
        const int gc = cbase + (fn << 4);
        const size_t o = (size_t)gr * ldc + gc;
        outH[o] = f2h(acc[fm][fn][j] + h2f(aux[o]));
      }
}

// ---------- apply stage BC (R3/R7-verified loop): 256x256 tile, BK=64,
// 8 waves (2x4), dbuf LDS, counted vmcnt(8). A = [R; P] stacked (lda 1024).
// Epilogue: gr<NU: C = v0[gr][gc] + 0.1*q[gr] - acc (x); else C = acc (y). ----------
__global__ __launch_bounds__(512, 2)
void gemm_bc(const u16* __restrict__ A, const u16* __restrict__ Bt,
             const float* __restrict__ v0, const float* __restrict__ qv,
             float* __restrict__ C, int lda, int ldb, int ldc,
             int M, int N, int K) {
  __shared__ u16 Al[2][256 * 64];
  __shared__ u16 Bl[2][256 * 64];

  const int nTm = M >> 8, nTn = N >> 8;
  const int nwg = nTm * nTn;
  int wg = (int)blockIdx.x;
  { const int c = nwg >> 3; wg = (wg & 7) * c + (wg >> 3); }  // XCD swizzle
  const int tm = wg % nTm, tn = wg / nTm;                     // tn-major
  const int row0 = tm << 8, col0 = tn << 8;

  const int tid = threadIdx.x;
  const int lane = tid & 63, wid = tid >> 6;
  const int wm = wid >> 2, wn = wid & 3;   // wave tile 128x64
  const int r16 = lane & 15, ch = lane >> 4;

  f32x4 acc[8][4] = {};

  auto stage = [&](const u16* __restrict__ G, int gld, int grow0, int k0, u16* lb) {
    #pragma unroll
    for (int h = 0; h < 4; ++h) {
      const int L = tid + (h << 9);
      const int row = L >> 3, seg = L & 7;
      const int ss = seg ^ (row & 7);
      gload16(G + (size_t)(grow0 + row) * gld + (size_t)(k0 + (ss << 3)),
              lb + ((L & ~63) << 3));
    }
  };

  const int nK = K >> 6;
  stage(A, lda, row0, 0, &Al[0][0]);
  stage(Bt, ldb, col0, 0, &Bl[0][0]);

  for (int t = 0; t < nK; ++t) {
    const int cur = t & 1;
    if (t + 1 < nK) {
      stage(A, lda, row0, (t + 1) << 6, &Al[cur ^ 1][0]);
      stage(Bt, ldb, col0, (t + 1) << 6, &Bl[cur ^ 1][0]);
      asm volatile("s_waitcnt vmcnt(8)" ::: "memory");
    } else {
      asm volatile("s_waitcnt vmcnt(0)" ::: "memory");
    }
    __builtin_amdgcn_sched_barrier(0);
    __builtin_amdgcn_s_barrier();
    __builtin_amdgcn_sched_barrier(0);

    #pragma unroll
    for (int kk = 0; kk < 2; ++kk) {
      bf16x8 av[8], bv[4];
      #pragma unroll
      for (int f = 0; f < 8; ++f) {
        const int ra = (wm << 7) + (f << 4) + r16;
        const int sa = ((kk << 2) + ch) ^ (ra & 7);
        av[f] = *(const bf16x8*)&Al[cur][(ra << 6) + (sa << 3)];
      }
      #pragma unroll
      for (int f = 0; f < 4; ++f) {
        const int rb = (wn << 6) + (f << 4) + r16;
        const int sb = ((kk << 2) + ch) ^ (rb & 7);
        bv[f] = *(const bf16x8*)&Bl[cur][(rb << 6) + (sb << 3)];
      }
      __builtin_amdgcn_s_setprio(1);
      #pragma unroll
      for (int fm = 0; fm < 8; ++fm)
        #pragma unroll
        for (int fn = 0; fn < 4; ++fn)
          acc[fm][fn] = __builtin_amdgcn_mfma_f32_16x16x32_bf16(av[fm], bv[fn], acc[fm][fn], 0, 0, 0);
      __builtin_amdgcn_s_setprio(0);
    }
    __builtin_amdgcn_sched_barrier(0);
    __builtin_amdgcn_s_barrier();
    __builtin_amdgcn_sched_barrier(0);
  }

  const int rbase = row0 + (wm << 7) + ((lane >> 4) << 2);
  const int cbase = col0 + (wn << 6) + (lane & 15);
  #pragma unroll
  for (int fm = 0; fm < 8; ++fm)
    #pragma unroll
    for (int fn = 0; fn < 4; ++fn)
      #pragma unroll
      for (int j = 0; j < 4; ++j) {
        const int gr = rbase + (fm << 4) + j;
        const int gc = cbase + (fn << 4);
        float vv = acc[fm][fn][j];
        if (gr < NU) vv = v0[(size_t)gr * ldc + gc] + 0.1f * qv[gr] - vv;
        C[(size_t)gr * ldc + gc] = vv;
      }
}

extern "C" void kernel_launch(void* const* d_in, const int* in_sizes, int n_in,
                              void* d_out, int out_size, void* d_ws, size_t ws_size,
                              hipStream_t stream) {
  (void)in_sizes; (void)n_in; (void)out_size; (void)ws_size;
  const float* v0 = (const float*)d_in[0];
  const float* v1 = (const float*)d_in[1];
  const float* B0 = (const float*)d_in[2];
  const float* q  = (const float*)d_in[3];
  float* out = (float*)d_out;

  size_t off = 0;
  char* base = (char*)d_ws;
  auto alloc = [&](size_t bytes) -> u16* {
    char* r = base + off;
    off += (bytes + 255) & ~(size_t)255;
    return (u16*)r;
  };
  u16* z1T  = alloc((size_t)NBB * NU * 2);   // 16.8 MB
  u16* z2T  = alloc((size_t)NBB * NU * 2);   // 16.8 MB
  u16* t1T  = alloc((size_t)NBB * NU * 2);   // 16.8 MB
  u16* SR   = alloc((size_t)2 * NU * NU * 2);// 4.2 MB: rows 0..1023 = R, 1024..2047 = P
  u16* B0h  = alloc((size_t)NU * NU * 2);
  u16* B0Th = alloc((size_t)NU * NU * 2);
  u16* B0Tl = alloc((size_t)NU * NU * 2);
  u16* Mh   = alloc((size_t)NU * NU * 2);
  u16* Ml   = alloc((size_t)NU * NU * 2);
  u16* S1   = alloc((size_t)NU * NU * 2);
  u16* S2   = alloc((size_t)NU * NU * 2);
  u16* S3   = alloc((size_t)NU * NU * 2);    // total ~71 MB

  u16* SR_lo = SR;                       // R
  u16* SR_hi = SR + (size_t)NU * NU;     // P

  const u16* NH = nullptr;

  prep_b0<<<dim3(32, 32), dim3(32, 8), 0, stream>>>(B0, B0h, B0Th, B0Tl);
  build_zT<<<dim3(NBB / 32, NU / 32), dim3(32, 8), 0, stream>>>(v0, v1, q, z1T, z2T);

  // M = 2I + B0^T B0 in split precision (hh + lh + hl) -> Mh + Ml
  gemm_s<4,2><<<256, 256, 0, stream>>>(B0Th, B0Tl, B0Th, B0Tl, NU, NU,
                                       NH, NU, 1.f, 0.f, 2.f, Mh, Ml, NU);
  // M2 = M*M (Bt = M, symmetric)
  gemm_s<2,3><<<256, 256, 0, stream>>>(Mh, nullptr, Mh, nullptr, NU, NU,
                                       NH, NU, 1.f, 0.f, 0.f, S1, nullptr, NU);
  // G = C2 I + C3 M + C4 M2
  build_g<<<NU * NU / 256, 256, 0, stream>>>(Mh, S1, S2);
  // X0 = M2*G + C1*M + C0*I   (Bt = G, symmetric; deg-4 Chebyshev, e0=0.036)
  gemm_s<2,3><<<256, 256, 0, stream>>>(S1, nullptr, S2, nullptr, NU, NU,
                                       Mh, NU, 1.f, C1, C0, S3, nullptr, NU);
  // E = I - M*X0              (split M; Bt = X0, symmetric)
  gemm_s<3,3><<<256, 256, 0, stream>>>(Mh, Ml, S3, nullptr, NU, NU,
                                       NH, NU, -1.f, 0.f, 1.f, S1, nullptr, NU);
  // P = X0 + X0*E             (Bt = E, symmetric) -> SR rows 1024..2047
  gemm_s<2,3><<<256, 256, 0, stream>>>(S3, nullptr, S1, nullptr, NU, NU,
                                       S3, NU, 1.f, 1.f, 0.f, SR_hi, nullptr, NU);
  // R = B0 * P                (Bt = P, symmetric) -> SR rows 0..1023
  gemm_s<2,3><<<256, 256, 0, stream>>>(B0h, nullptr, SR_hi, nullptr, NU, NU,
                                       NH, NU, 1.f, 0.f, 0.f, SR_lo, nullptr, NU);

  // apply A: t1T = z1T * B0 + z2T   (8192 x 1024 x 1024, 512 WGs, 2 blk/CU)
  gemm_a<<<(NBB / 128) * (NU / 128), 256, 0, stream>>>(
      z1T, B0Th, z2T, t1T, NU, NU, NU, NBB, NU, NU);
  // apply BC: [x; y] = [z1 - R t1 ; P t1]   (2048 x 8192 x 1024, 256 WGs)
  gemm_bc<<<(2 * NU / 256) * (NBB / 256), 512, 0, stream>>>(
      SR, t1T, v0, q, out, NU, NU, NBB, 2 * NU, NBB, NU);
}

// Round 11
// 181.939 us; speedup vs baseline: 1.0060x; 1.0060x over previous
//
#include <hip/hip_runtime.h>
#include <stdint.h>

typedef unsigned short u16;
typedef __bf16 bf16x8 __attribute__((ext_vector_type(8)));
typedef float f32x4 __attribute__((ext_vector_type(4)));
typedef __attribute__((address_space(3))) void as3_void;
typedef __attribute__((address_space(1))) void as1_void;

#define NU   1024
#define NBB  8192
#define LDW  2048

// Degree-4 constrained-Chebyshev init for 1/lambda on [2, 13.8]:
// X0 = C0*I + C1*M + M^2*(C2*I + C3*M + C4*M^2), e0 = 0.0363
#define C0 0.9513167f
#define C1 (-0.3169175f)
#define C2 0.0471891f
#define C3 (-0.00321059f)
#define C4 0.00008127825f

// ---------- bf16 helpers (RNE, bit ops; inputs finite) ----------
__device__ __forceinline__ u16 f2h(float f) {
  union { float f; uint32_t u; } c; c.f = f;
  uint32_t r = (c.u + 0x7fffu + ((c.u >> 16) & 1u)) >> 16;
  return (u16)r;
}
__device__ __forceinline__ float h2f(u16 h) {
  union { uint32_t u; float f; } c; c.u = ((uint32_t)h) << 16;
  return c.f;
}

__device__ __forceinline__ void gload16(const u16* g, u16* l) {
  __builtin_amdgcn_global_load_lds((const as1_void*)g, (as3_void*)l, 16, 0, 0);
}

// ---------- prep: B0 -> bf16 B0h (plain hi), B0Th/B0Tl (transposed hi/lo) ----------
__global__ void prep_b0(const float* __restrict__ B0, u16* __restrict__ B0h,
                        u16* __restrict__ B0Th, u16* __restrict__ B0Tl) {
  __shared__ float t[32][33];
  const int bx = blockIdx.x, by = blockIdx.y;
  const int x = threadIdx.x, y0 = threadIdx.y;
  #pragma unroll
  for (int yy = y0; yy < 32; yy += 8) {
    const int r = by * 32 + yy, c = bx * 32 + x;
    const float v = B0[(size_t)r * NU + c];
    t[yy][x] = v;
    B0h[(size_t)r * NU + c] = f2h(v);
  }
  __syncthreads();
  #pragma unroll
  for (int yy = y0; yy < 32; yy += 8) {
    const int r = bx * 32 + yy, c = by * 32 + x;  // B0T[r][c] = B0[c][r]
    const float v = t[x][yy];
    const u16 hh = f2h(v);
    B0Th[(size_t)r * NU + c] = hh;
    B0Tl[(size_t)r * NU + c] = f2h(v - h2f(hh));
  }
}

// ---------- zzT[b][i] = z1, zzT[b][i+NU] = z2 (transposed, bf16) ----------
__global__ void build_zzT(const float* __restrict__ v0, const float* __restrict__ v1,
                          const float* __restrict__ q, u16* __restrict__ zzT) {
  __shared__ u16 s1[32][33], s2[32][33];
  const int bx = blockIdx.x;  // batch tile
  const int by = blockIdx.y;  // unit tile
  const int x = threadIdx.x, y0 = threadIdx.y;
  #pragma unroll
  for (int yy = y0; yy < 32; yy += 8) {
    const int i = by * 32 + yy;
    const int b = bx * 32 + x;
    const float a0 = v0[(size_t)i * NBB + b];
    const float a1 = v1[(size_t)i * NBB + b];
    s1[yy][x] = f2h(a0 + 0.1f * q[i]);
    s2[yy][x] = f2h(a1 + tanhf(a0));
  }
  __syncthreads();
  #pragma unroll
  for (int yy = y0; yy < 32; yy += 8) {
    const int b = bx * 32 + yy;
    const int i = by * 32 + x;
    zzT[(size_t)b * LDW + i]      = s1[x][yy];
    zzT[(size_t)b * LDW + NU + i] = s2[x][yy];
  }
}

// ---------- bf16 1024x1024 transpose with ld + optional negate ----------
__global__ void transpose_f(const u16* __restrict__ in, int ldi,
                            u16* __restrict__ out, int ldo, int flip) {
  __shared__ u16 t[32][33];
  const int bx = blockIdx.x, by = blockIdx.y;
  const int x = threadIdx.x, y0 = threadIdx.y;
  #pragma unroll
  for (int yy = y0; yy < 32; yy += 8)
    t[yy][x] = in[(size_t)(by * 32 + yy) * ldi + bx * 32 + x];
  __syncthreads();
  const u16 m = flip ? (u16)0x8000u : (u16)0;
  #pragma unroll
  for (int yy = y0; yy < 32; yy += 8)
    out[(size_t)(bx * 32 + yy) * ldo + by * 32 + x] = (u16)(t[x][yy] ^ m);
}

// ---------- small setup GEMM v2: 64x32 tile, grid 512 (2-3 blocks/CU),
// BK=128, 4 waves (2x2, wave tile 32x16), dbuf LDS, issue-early staging,
// counted vmcnt. C = A * Bt^T, 1024^3 shapes (lda/ldb/ldc params).
// NOPS: 2 = A0*B0; 3 = (A0+A1)*B0; 4 = A0B0 + A1B0 + A0B1 (split precision).
// EMODE 0: outH = bf16(alpha*acc + beta*aux + gamma*I), outL = lo-split.
// EMODE 1: outH = bf16(acc)  [M2], outL = bf16(C4*acc + C3*aux + C2*I) [G]. ----------
template<int NOPS, int EMODE>
__global__ __launch_bounds__(256, 2)
void gemm_s2(const u16* __restrict__ A0, const u16* __restrict__ A1,
             const u16* __restrict__ Bt0, const u16* __restrict__ Bt1,
             int lda, int ldb,
             const u16* __restrict__ aux, int ldaux,
             float alpha, float beta, float gamma,
             u16* __restrict__ outH, u16* __restrict__ outL, int ldc) {
  constexpr int BK = 128;
  constexpr int NA = (NOPS >= 3) ? 2 : 1;
  constexpr int NB2 = (NOPS == 4) ? 2 : 1;
  constexpr int RA = 4;            // 64*128 / (256*8)
  constexpr int RB = 2;            // 32*128 / (256*8)
  constexpr int LOADS = RA * NA + RB * NB2;
  __shared__ u16 Al[2][NA][64 * BK];   // 16 KB per buf per op
  __shared__ u16 Bl[2][NB2][32 * BK];  // 8 KB per buf per op

  int wg = (int)blockIdx.x;
  { wg = (wg & 7) * 64 + (wg >> 3); }  // XCD swizzle, grid 512
  const int tm = wg & 15, tn = wg >> 4;   // nTm=16, nTn=32
  const int row0 = tm << 6, col0 = tn << 5;

  const int tid = threadIdx.x;
  const int lane = tid & 63, wid = tid >> 6;
  const int wm = wid >> 1, wn = wid & 1;  // wave tile 32x16
  const int r16 = lane & 15, ch = lane >> 4;

  f32x4 acc[2] = {};

  auto stageAll = [&](int k0, int buf) {
    #pragma unroll
    for (int h = 0; h < RA; ++h) {
      const int L = tid + (h << 8);
      const int row = L >> 4;                 // 16 segs of 8 elems per row
      const int ss = (L & 15) ^ (row & 7);
      const size_t go = (size_t)(row0 + row) * lda + (size_t)(k0 + (ss << 3));
      gload16(A0 + go, &Al[buf][0][(L & ~63) << 3]);
      if constexpr (NA == 2) gload16(A1 + go, &Al[buf][1][(L & ~63) << 3]);
    }
    #pragma unroll
    for (int h = 0; h < RB; ++h) {
      const int L = tid + (h << 8);
      const int row = L >> 4;
      const int ss = (L & 15) ^ (row & 7);
      const size_t go = (size_t)(col0 + row) * ldb + (size_t)(k0 + (ss << 3));
      gload16(Bt0 + go, &Bl[buf][0][(L & ~63) << 3]);
      if constexpr (NB2 == 2) gload16(Bt1 + go, &Bl[buf][1][(L & ~63) << 3]);
    }
  };

  const int nK = 1024 / BK;  // 8
  stageAll(0, 0);

  for (int t = 0; t < nK; ++t) {
    const int cur = t & 1;
    if (t + 1 < nK) {
      stageAll((t + 1) * BK, cur ^ 1);
      if constexpr (LOADS == 6)       asm volatile("s_waitcnt vmcnt(6)" ::: "memory");
      else if constexpr (LOADS == 10) asm volatile("s_waitcnt vmcnt(10)" ::: "memory");
      else                            asm volatile("s_waitcnt vmcnt(12)" ::: "memory");
    } else {
      asm volatile("s_waitcnt vmcnt(0)" ::: "memory");
    }
    __builtin_amdgcn_sched_barrier(0);
    __builtin_amdgcn_s_barrier();
    __builtin_amdgcn_sched_barrier(0);

    #pragma unroll
    for (int kk = 0; kk < BK / 32; ++kk) {
      bf16x8 av[2], av1[2], bv, bv1;
      #pragma unroll
      for (int f = 0; f < 2; ++f) {
        const int ra = (wm << 5) + (f << 4) + r16;
        const int sa = ((kk << 2) + ch) ^ (ra & 7);
        av[f] = *(const bf16x8*)&Al[cur][0][ra * BK + (sa << 3)];
        if constexpr (NA == 2)
          av1[f] = *(const bf16x8*)&Al[cur][1][ra * BK + (sa << 3)];
      }
      {
        const int rb = (wn << 4) + r16;
        const int sb = ((kk << 2) + ch) ^ (rb & 7);
        bv = *(const bf16x8*)&Bl[cur][0][rb * BK + (sb << 3)];
        if constexpr (NB2 == 2)
          bv1 = *(const bf16x8*)&Bl[cur][1][rb * BK + (sb << 3)];
      }
      __builtin_amdgcn_s_setprio(1);
      #pragma unroll
      for (int fm = 0; fm < 2; ++fm)
        acc[fm] = __builtin_amdgcn_mfma_f32_16x16x32_bf16(av[fm], bv, acc[fm], 0, 0, 0);
      if constexpr (NA == 2) {
        #pragma unroll
        for (int fm = 0; fm < 2; ++fm)
          acc[fm] = __builtin_amdgcn_mfma_f32_16x16x32_bf16(av1[fm], bv, acc[fm], 0, 0, 0);
      }
      if constexpr (NB2 == 2) {
        #pragma unroll
        for (int fm = 0; fm < 2; ++fm)
          acc[fm] = __builtin_amdgcn_mfma_f32_16x16x32_bf16(av[fm], bv1, acc[fm], 0, 0, 0);
      }
      __builtin_amdgcn_s_setprio(0);
    }
    __builtin_amdgcn_sched_barrier(0);
    __builtin_amdgcn_s_barrier();
    __builtin_amdgcn_sched_barrier(0);
  }

  // epilogue: C/D layout: col = lane&15, row = (lane>>4)*4 + j
  const int rbase = row0 + (wm << 5) + ((lane >> 4) << 2);
  const int cbase = col0 + (wn << 4) + (lane & 15);
  #pragma unroll
  for (int fm = 0; fm < 2; ++fm)
    #pragma unroll
    for (int j = 0; j < 4; ++j) {
      const int gr = rbase + (fm << 4) + j;
      const int gc = cbase;
      const float a = acc[fm][j];
      if constexpr (EMODE == 0) {
        float v = alpha * a;
        if (aux) v += beta * h2f(aux[(size_t)gr * ldaux + gc]);
        if (gamma != 0.f && gr == gc) v += gamma;
        const u16 hh = f2h(v);
        outH[(size_t)gr * ldc + gc] = hh;
        if (outL) outL[(size_t)gr * ldc + gc] = f2h(v - h2f(hh));
      } else {
        // M2 + fused G = C2*I + C3*M + C4*M2 (from fp32 acc)
        outH[(size_t)gr * ldc + gc] = f2h(a);
        float g = C4 * a + C3 * h2f(aux[(size_t)gr * ldaux + gc]);
        if (gr == gc) g += C2;
        outL[(size_t)gr * ldc + gc] = f2h(g);
      }
    }
}

// ---------- apply GEMM (R3/R7/R9-verified, 80-81.5 us): 256x256 tile, BK=64,
// 8 waves (2x4), dbuf LDS, issue-early staging + counted vmcnt(8), raw barriers.
// C (fp32) = A (bf16 [M][K]) * Bt^T (bf16 [N][K]) ----------
__global__ __launch_bounds__(512, 2)
void gemm_apply(const u16* __restrict__ A, const u16* __restrict__ Bt,
                float* __restrict__ C, int lda, int ldb, int ldc,
                int M, int N, int K) {
  __shared__ u16 Al[2][256 * 64];
  __shared__ u16 Bl[2][256 * 64];

  const int nTm = M >> 8, nTn = N >> 8;
  const int nwg = nTm * nTn;
  int wg = (int)blockIdx.x;
  { const int c = nwg >> 3; wg = (wg & 7) * c + (wg >> 3); }  // XCD swizzle
  const int tm = wg % nTm, tn = wg / nTm;                     // tn-major
  const int row0 = tm << 8, col0 = tn << 8;

  const int tid = threadIdx.x;
  const int lane = tid & 63, wid = tid >> 6;
  const int wm = wid >> 2, wn = wid & 3;   // wave tile 128x64
  const int r16 = lane & 15, ch = lane >> 4;

  f32x4 acc[8][4] = {};

  auto stage = [&](const u16* __restrict__ G, int gld, int grow0, int k0, u16* lb) {
    #pragma unroll
    for (int h = 0; h < 4; ++h) {
      const int L = tid + (h << 9);
      const int row = L >> 3, seg = L & 7;
      const int ss = seg ^ (row & 7);
      gload16(G + (size_t)(grow0 + row) * gld + (size_t)(k0 + (ss << 3)),
              lb + ((L & ~63) << 3));
    }
  };

  const int nK = K >> 6;
  stage(A, lda, row0, 0, &Al[0][0]);
  stage(Bt, ldb, col0, 0, &Bl[0][0]);

  for (int t = 0; t < nK; ++t) {
    const int cur = t & 1;
    if (t + 1 < nK) {
      stage(A, lda, row0, (t + 1) << 6, &Al[cur ^ 1][0]);
      stage(Bt, ldb, col0, (t + 1) << 6, &Bl[cur ^ 1][0]);
      asm volatile("s_waitcnt vmcnt(8)" ::: "memory");  // tile t landed; t+1 in flight
    } else {
      asm volatile("s_waitcnt vmcnt(0)" ::: "memory");
    }
    __builtin_amdgcn_sched_barrier(0);
    __builtin_amdgcn_s_barrier();
    __builtin_amdgcn_sched_barrier(0);

    #pragma unroll
    for (int kk = 0; kk < 2; ++kk) {
      bf16x8 av[8], bv[4];
      #pragma unroll
      for (int f = 0; f < 8; ++f) {
        const int ra = (wm << 7) + (f << 4) + r16;
        const int sa = ((kk << 2) + ch) ^ (ra & 7);
        av[f] = *(const bf16x8*)&Al[cur][(ra << 6) + (sa << 3)];
      }
      #pragma unroll
      for (int f = 0; f < 4; ++f) {
        const int rb = (wn << 6) + (f << 4) + r16;
        const int sb = ((kk << 2) + ch) ^ (rb & 7);
        bv[f] = *(const bf16x8*)&Bl[cur][(rb << 6) + (sb << 3)];
      }
      __builtin_amdgcn_s_setprio(1);
      #pragma unroll
      for (int fm = 0; fm < 8; ++fm)
        #pragma unroll
        for (int fn = 0; fn < 4; ++fn)
          acc[fm][fn] = __builtin_amdgcn_mfma_f32_16x16x32_bf16(av[fm], bv[fn], acc[fm][fn], 0, 0, 0);
      __builtin_amdgcn_s_setprio(0);
    }
    __builtin_amdgcn_sched_barrier(0);
    __builtin_amdgcn_s_barrier();
    __builtin_amdgcn_sched_barrier(0);
  }

  const int rbase = row0 + (wm << 7) + ((lane >> 4) << 2);
  const int cbase = col0 + (wn << 6) + (lane & 15);
  #pragma unroll
  for (int fm = 0; fm < 8; ++fm)
    #pragma unroll
    for (int fn = 0; fn < 4; ++fn)
      #pragma unroll
      for (int j = 0; j < 4; ++j) {
        const int gr = rbase + (fm << 4) + j;
        const int gc = cbase + (fn << 4);
        C[(size_t)gr * ldc + gc] = acc[fm][fn][j];
      }
}

extern "C" void kernel_launch(void* const* d_in, const int* in_sizes, int n_in,
                              void* d_out, int out_size, void* d_ws, size_t ws_size,
                              hipStream_t stream) {
  (void)in_sizes; (void)n_in; (void)out_size; (void)ws_size;
  const float* v0 = (const float*)d_in[0];
  const float* v1 = (const float*)d_in[1];
  const float* B0 = (const float*)d_in[2];
  const float* q  = (const float*)d_in[3];
  float* out = (float*)d_out;

  size_t off = 0;
  char* base = (char*)d_ws;
  auto alloc = [&](size_t bytes) -> u16* {
    char* r = base + off;
    off += (bytes + 255) & ~(size_t)255;
    return (u16*)r;
  };
  u16* zzT  = alloc((size_t)NBB * LDW * 2);  // 33.6 MB
  u16* Wb   = alloc((size_t)LDW * LDW * 2);  //  8.4 MB
  u16* B0h  = alloc((size_t)NU * NU * 2);
  u16* B0Th = alloc((size_t)NU * NU * 2);
  u16* B0Tl = alloc((size_t)NU * NU * 2);
  u16* Mh   = alloc((size_t)NU * NU * 2);
  u16* Ml   = alloc((size_t)NU * NU * 2);
  u16* S1   = alloc((size_t)NU * NU * 2);
  u16* S2   = alloc((size_t)NU * NU * 2);
  u16* S3   = alloc((size_t)NU * NU * 2);   // total ~59 MB

  // Wbig quadrants: [[ I + (-R)B0^T , -R ], [ Q , P ]],  R = B0 P, Q = P B0^T
  u16* WbTL = Wb;
  u16* WbTR = Wb + NU;
  u16* WbBL = Wb + (size_t)NU * LDW;
  u16* WbBR = Wb + (size_t)NU * LDW + NU;

  const u16* NH = nullptr;

  prep_b0<<<dim3(32, 32), dim3(32, 8), 0, stream>>>(B0, B0h, B0Th, B0Tl);
  build_zzT<<<dim3(NBB / 32, NU / 32), dim3(32, 8), 0, stream>>>(v0, v1, q, zzT);

  // M = 2I + B0^T B0 in split precision (hh + lh + hl) -> Mh + Ml
  gemm_s2<4,0><<<512, 256, 0, stream>>>(B0Th, B0Tl, B0Th, B0Tl, NU, NU,
                                        NH, NU, 1.f, 0.f, 2.f, Mh, Ml, NU);
  // M2 = M*M -> S1; fused G = C2 I + C3 M + C4 M2 -> S2  (Bt = M, symmetric)
  gemm_s2<2,1><<<512, 256, 0, stream>>>(Mh, nullptr, Mh, nullptr, NU, NU,
                                        Mh, NU, 1.f, 0.f, 0.f, S1, S2, NU);
  // X0 = M2*G + C1*M + C0*I   (Bt = G, symmetric; deg-4 Chebyshev, e0=0.036)
  gemm_s2<2,0><<<512, 256, 0, stream>>>(S1, nullptr, S2, nullptr, NU, NU,
                                        Mh, NU, 1.f, C1, C0, S3, nullptr, NU);
  // E = I - M*X0              (split M; Bt = X0, symmetric)
  gemm_s2<3,0><<<512, 256, 0, stream>>>(Mh, Ml, S3, nullptr, NU, NU,
                                        NH, NU, -1.f, 0.f, 1.f, S1, nullptr, NU);
  // P = X0 + X0*E             (Bt = E, symmetric) -> Wbig BR (ldc = 2048)
  gemm_s2<2,0><<<512, 256, 0, stream>>>(S3, nullptr, S1, nullptr, NU, NU,
                                        S3, NU, 1.f, 1.f, 0.f, WbBR, nullptr, LDW);
  // -R = -(B0 * P)            (Bt = P, symmetric; read from Wb) -> Wbig TR
  gemm_s2<2,0><<<512, 256, 0, stream>>>(B0h, nullptr, WbBR, nullptr, NU, LDW,
                                        NH, NU, -1.f, 0.f, 0.f, WbTR, nullptr, LDW);
  // Q = P B0^T = -(-R)^T -> Wbig BL (flip-transpose, no GEMM)
  transpose_f<<<dim3(32, 32), dim3(32, 8), 0, stream>>>(WbTR, LDW, WbBL, LDW, 1);
  // TL = I + (-R)*B0^T        (Bt = B0, gamma = 1) -> Wbig TL
  gemm_s2<2,0><<<512, 256, 0, stream>>>(WbTR, nullptr, B0h, nullptr, LDW, NU,
                                        NH, NU, 1.f, 0.f, 1.f, WbTL, nullptr, LDW);

  // apply: out = Wbig * zzT^T  (2048 x 8192 x 2048)
  gemm_apply<<<(LDW / 256) * (NBB / 256), 512, 0, stream>>>(
      Wb, zzT, out, LDW, LDW, NBB, LDW, NBB, LDW);
}

// Round 12
// 169.884 us; speedup vs baseline: 1.0773x; 1.0710x over previous
//
#include <hip/hip_runtime.h>
#include <stdint.h>

typedef unsigned short u16;
typedef __bf16 bf16x8 __attribute__((ext_vector_type(8)));
typedef float f32x4 __attribute__((ext_vector_type(4)));
typedef __attribute__((address_space(3))) void as3_void;
typedef __attribute__((address_space(1))) void as1_void;

#define NU   1024
#define NBB  8192
#define LDW  2048

// Degree-4 constrained-Chebyshev init for 1/lambda on [2, 13.8]:
// X0 = C0*I + C1*M + M^2*(C2*I + C3*M + C4*M^2), e0 = 0.0363
#define C0 0.9513167f
#define C1 (-0.3169175f)
#define C2 0.0471891f
#define C3 (-0.00321059f)
#define C4 0.00008127825f

// ---------- bf16 helpers (RNE, bit ops; inputs finite) ----------
__device__ __forceinline__ u16 f2h(float f) {
  union { float f; uint32_t u; } c; c.f = f;
  uint32_t r = (c.u + 0x7fffu + ((c.u >> 16) & 1u)) >> 16;
  return (u16)r;
}
__device__ __forceinline__ float h2f(u16 h) {
  union { uint32_t u; float f; } c; c.u = ((uint32_t)h) << 16;
  return c.f;
}

__device__ __forceinline__ void gload16(const u16* g, u16* l) {
  __builtin_amdgcn_global_load_lds((const as1_void*)g, (as3_void*)l, 16, 0, 0);
}

// ---------- prep: B0 -> bf16 B0h (plain hi), B0Th/B0Tl (transposed hi/lo) ----------
__global__ void prep_b0(const float* __restrict__ B0, u16* __restrict__ B0h,
                        u16* __restrict__ B0Th, u16* __restrict__ B0Tl) {
  __shared__ float t[32][33];
  const int bx = blockIdx.x, by = blockIdx.y;
  const int x = threadIdx.x, y0 = threadIdx.y;
  #pragma unroll
  for (int yy = y0; yy < 32; yy += 8) {
    const int r = by * 32 + yy, c = bx * 32 + x;
    const float v = B0[(size_t)r * NU + c];
    t[yy][x] = v;
    B0h[(size_t)r * NU + c] = f2h(v);
  }
  __syncthreads();
  #pragma unroll
  for (int yy = y0; yy < 32; yy += 8) {
    const int r = bx * 32 + yy, c = by * 32 + x;  // B0T[r][c] = B0[c][r]
    const float v = t[x][yy];
    const u16 hh = f2h(v);
    B0Th[(size_t)r * NU + c] = hh;
    B0Tl[(size_t)r * NU + c] = f2h(v - h2f(hh));
  }
}

// ---------- zzT[b][i] = z1, zzT[b][i+NU] = z2 (transposed, bf16) ----------
__global__ void build_zzT(const float* __restrict__ v0, const float* __restrict__ v1,
                          const float* __restrict__ q, u16* __restrict__ zzT) {
  __shared__ u16 s1[32][33], s2[32][33];
  const int bx = blockIdx.x;  // batch tile
  const int by = blockIdx.y;  // unit tile
  const int x = threadIdx.x, y0 = threadIdx.y;
  #pragma unroll
  for (int yy = y0; yy < 32; yy += 8) {
    const int i = by * 32 + yy;
    const int b = bx * 32 + x;
    const float a0 = v0[(size_t)i * NBB + b];
    const float a1 = v1[(size_t)i * NBB + b];
    s1[yy][x] = f2h(a0 + 0.1f * q[i]);
    s2[yy][x] = f2h(a1 + tanhf(a0));
  }
  __syncthreads();
  #pragma unroll
  for (int yy = y0; yy < 32; yy += 8) {
    const int b = bx * 32 + yy;
    const int i = by * 32 + x;
    zzT[(size_t)b * LDW + i]      = s1[x][yy];
    zzT[(size_t)b * LDW + NU + i] = s2[x][yy];
  }
}

// ---------- bf16 1024x1024 transpose with ld + optional negate ----------
__global__ void transpose_f(const u16* __restrict__ in, int ldi,
                            u16* __restrict__ out, int ldo, int flip) {
  __shared__ u16 t[32][33];
  const int bx = blockIdx.x, by = blockIdx.y;
  const int x = threadIdx.x, y0 = threadIdx.y;
  #pragma unroll
  for (int yy = y0; yy < 32; yy += 8)
    t[yy][x] = in[(size_t)(by * 32 + yy) * ldi + bx * 32 + x];
  __syncthreads();
  const u16 m = flip ? (u16)0x8000u : (u16)0;
  #pragma unroll
  for (int yy = y0; yy < 32; yy += 8)
    out[(size_t)(bx * 32 + yy) * ldo + by * 32 + x] = (u16)(t[x][yy] ^ m);
}

// ---------- small setup GEMM (R9-verified): 64x64 tile, BK=128, 4 waves,
// PDIST-deep prefetch, issue-early staging, counted vmcnt. C = A * Bt^T, 1024^3.
// NOPS: 2 = A0*B0; 3 = (A0+A1)*B0; 4 = A0B0 + A1B0 + A0B1 (split precision).
// EMODE 0: outH(+outL lo-split) = bf16(alpha*acc + beta*aux + gamma*I).
// EMODE 1: outH = bf16(acc) [M2]; outL = bf16(C4*acc + C3*aux + C2*I) [G]. ----------
template<int NOPS, int PDIST, int EMODE>
__global__ __launch_bounds__(256, 1)
void gemm_s(const u16* __restrict__ A0, const u16* __restrict__ A1,
            const u16* __restrict__ Bt0, const u16* __restrict__ Bt1,
            int lda, int ldb,
            const u16* __restrict__ aux, int ldaux,
            float alpha, float beta, float gamma,
            u16* __restrict__ outH, u16* __restrict__ outL, int ldc) {
  constexpr int BK = 128;          // K-step
  constexpr int NA = (NOPS >= 3) ? 2 : 1;
  constexpr int NB2 = (NOPS == 4) ? 2 : 1;
  constexpr int RA = 4;            // 64*128 elems / (256 thr * 8 elems)
  constexpr int LOADS = RA * (NA + NB2);
  __shared__ u16 Al[PDIST][NA][64 * BK];
  __shared__ u16 Bl[PDIST][NB2][64 * BK];

  int wg = (int)blockIdx.x;
  { wg = (wg & 7) * 32 + (wg >> 3); }  // XCD swizzle, grid 256
  const int tm = wg & 15, tn = wg >> 4;
  const int row0 = tm << 6, col0 = tn << 6;

  const int tid = threadIdx.x;
  const int lane = tid & 63, wid = tid >> 6;
  const int wm = wid >> 1, wn = wid & 1;
  const int r16 = lane & 15, ch = lane >> 4;

  f32x4 acc[2][2] = {};

  auto stageAll = [&](int k0, int buf) {
    #pragma unroll
    for (int h = 0; h < RA; ++h) {
      const int L = tid + (h << 8);
      const int row = L >> 4;                 // 16 segs of 8 elems per row
      const int ss = (L & 15) ^ (row & 7);
      const size_t go = (size_t)(row0 + row) * lda + (size_t)(k0 + (ss << 3));
      gload16(A0 + go, &Al[buf][0][(L & ~63) << 3]);
      if constexpr (NA == 2) gload16(A1 + go, &Al[buf][1][(L & ~63) << 3]);
    }
    #pragma unroll
    for (int h = 0; h < RA; ++h) {
      const int L = tid + (h << 8);
      const int row = L >> 4;
      const int ss = (L & 15) ^ (row & 7);
      const size_t go = (size_t)(col0 + row) * ldb + (size_t)(k0 + (ss << 3));
      gload16(Bt0 + go, &Bl[buf][0][(L & ~63) << 3]);
      if constexpr (NB2 == 2) gload16(Bt1 + go, &Bl[buf][1][(L & ~63) << 3]);
    }
  };

  const int nK = 1024 / BK;  // 8
  stageAll(0, 0);
  if constexpr (PDIST == 3) stageAll(BK, 1);

  int cur = 0;
  for (int t = 0; t < nK; ++t) {
    int bs = cur + (PDIST - 1); if (bs >= PDIST) bs -= PDIST;
    if (t + PDIST - 1 < nK) {
      stageAll((t + PDIST - 1) * BK, bs);
      if constexpr (PDIST == 2) {
        if constexpr (LOADS == 8)  asm volatile("s_waitcnt vmcnt(8)" ::: "memory");
        else if constexpr (LOADS == 12) asm volatile("s_waitcnt vmcnt(12)" ::: "memory");
        else asm volatile("s_waitcnt vmcnt(16)" ::: "memory");
      } else {
        if constexpr (LOADS == 8)  asm volatile("s_waitcnt vmcnt(16)" ::: "memory");
        else asm volatile("s_waitcnt vmcnt(24)" ::: "memory");
      }
    } else if (PDIST == 3 && t + 1 < nK) {
      if constexpr (LOADS == 8)  asm volatile("s_waitcnt vmcnt(8)" ::: "memory");
      else asm volatile("s_waitcnt vmcnt(12)" ::: "memory");
    } else {
      asm volatile("s_waitcnt vmcnt(0)" ::: "memory");
    }
    __builtin_amdgcn_sched_barrier(0);
    __builtin_amdgcn_s_barrier();
    __builtin_amdgcn_sched_barrier(0);

    #pragma unroll
    for (int kk = 0; kk < BK / 32; ++kk) {
      bf16x8 av[2], bv[2], av1[2], bv1[2];
      #pragma unroll
      for (int f = 0; f < 2; ++f) {
        const int ra = (wm << 5) + (f << 4) + r16;
        const int sa = ((kk << 2) + ch) ^ (ra & 7);
        av[f] = *(const bf16x8*)&Al[cur][0][ra * BK + (sa << 3)];
        if constexpr (NA == 2)
          av1[f] = *(const bf16x8*)&Al[cur][1][ra * BK + (sa << 3)];
        const int rb = (wn << 5) + (f << 4) + r16;
        const int sb = ((kk << 2) + ch) ^ (rb & 7);
        bv[f] = *(const bf16x8*)&Bl[cur][0][rb * BK + (sb << 3)];
        if constexpr (NB2 == 2)
          bv1[f] = *(const bf16x8*)&Bl[cur][1][rb * BK + (sb << 3)];
      }
      __builtin_amdgcn_s_setprio(1);
      #pragma unroll
      for (int fm = 0; fm < 2; ++fm)
        #pragma unroll
        for (int fn = 0; fn < 2; ++fn)
          acc[fm][fn] = __builtin_amdgcn_mfma_f32_16x16x32_bf16(av[fm], bv[fn], acc[fm][fn], 0, 0, 0);
      if constexpr (NA == 2) {
        #pragma unroll
        for (int fm = 0; fm < 2; ++fm)
          #pragma unroll
          for (int fn = 0; fn < 2; ++fn)
            acc[fm][fn] = __builtin_amdgcn_mfma_f32_16x16x32_bf16(av1[fm], bv[fn], acc[fm][fn], 0, 0, 0);
      }
      if constexpr (NB2 == 2) {
        #pragma unroll
        for (int fm = 0; fm < 2; ++fm)
          #pragma unroll
          for (int fn = 0; fn < 2; ++fn)
            acc[fm][fn] = __builtin_amdgcn_mfma_f32_16x16x32_bf16(av[fm], bv1[fn], acc[fm][fn], 0, 0, 0);
      }
      __builtin_amdgcn_s_setprio(0);
    }
    __builtin_amdgcn_sched_barrier(0);
    __builtin_amdgcn_s_barrier();
    __builtin_amdgcn_sched_barrier(0);
    ++cur; if (cur == PDIST) cur = 0;
  }

  // epilogue: C/D layout: col = lane&15, row = (lane>>4)*4 + j
  const int rbase = row0 + (wm << 5) + ((lane >> 4) << 2);
  const int cbase = col0 + (wn << 5) + (lane & 15);
  #pragma unroll
  for (int fm = 0; fm < 2; ++fm)
    #pragma unroll
    for (int fn = 0; fn < 2; ++fn)
      #pragma unroll
      for (int j = 0; j < 4; ++j) {
        const int gr = rbase + (fm << 4) + j;
        const int gc = cbase + (fn << 4);
        const float a = acc[fm][fn][j];
        if constexpr (EMODE == 0) {
          float v = alpha * a;
          if (aux) v += beta * h2f(aux[(size_t)gr * ldaux + gc]);
          if (gamma != 0.f && gr == gc) v += gamma;
          const u16 hh = f2h(v);
          outH[(size_t)gr * ldc + gc] = hh;
          if (outL) outL[(size_t)gr * ldc + gc] = f2h(v - h2f(hh));
        } else {
          // fused: outH = M2, outL = G = C2*I + C3*M + C4*M2 (from fp32 acc)
          outH[(size_t)gr * ldc + gc] = f2h(a);
          float g = C4 * a + C3 * h2f(aux[(size_t)gr * ldaux + gc]);
          if (gr == gc) g += C2;
          outL[(size_t)gr * ldc + gc] = f2h(g);
        }
      }
}

// ---------- apply GEMM (R3/R7/R9/R11-verified, 80-81.5 us): 256x256 tile,
// BK=64, 8 waves (2x4), dbuf LDS, issue-early staging + counted vmcnt(8),
// raw barriers. C (fp32) = A (bf16 [M][K]) * Bt^T (bf16 [N][K]) ----------
__global__ __launch_bounds__(512, 2)
void gemm_apply(const u16* __restrict__ A, const u16* __restrict__ Bt,
                float* __restrict__ C, int lda, int ldb, int ldc,
                int M, int N, int K) {
  __shared__ u16 Al[2][256 * 64];
  __shared__ u16 Bl[2][256 * 64];

  const int nTm = M >> 8, nTn = N >> 8;
  const int nwg = nTm * nTn;
  int wg = (int)blockIdx.x;
  { const int c = nwg >> 3; wg = (wg & 7) * c + (wg >> 3); }  // XCD swizzle
  const int tm = wg % nTm, tn = wg / nTm;                     // tn-major
  const int row0 = tm << 8, col0 = tn << 8;

  const int tid = threadIdx.x;
  const int lane = tid & 63, wid = tid >> 6;
  const int wm = wid >> 2, wn = wid & 3;   // wave tile 128x64
  const int r16 = lane & 15, ch = lane >> 4;

  f32x4 acc[8][4] = {};

  auto stage = [&](const u16* __restrict__ G, int gld, int grow0, int k0, u16* lb) {
    #pragma unroll
    for (int h = 0; h < 4; ++h) {
      const int L = tid + (h << 9);
      const int row = L >> 3, seg = L & 7;
      const int ss = seg ^ (row & 7);
      gload16(G + (size_t)(grow0 + row) * gld + (size_t)(k0 + (ss << 3)),
              lb + ((L & ~63) << 3));
    }
  };

  const int nK = K >> 6;
  stage(A, lda, row0, 0, &Al[0][0]);
  stage(Bt, ldb, col0, 0, &Bl[0][0]);

  for (int t = 0; t < nK; ++t) {
    const int cur = t & 1;
    if (t + 1 < nK) {
      stage(A, lda, row0, (t + 1) << 6, &Al[cur ^ 1][0]);
      stage(Bt, ldb, col0, (t + 1) << 6, &Bl[cur ^ 1][0]);
      asm volatile("s_waitcnt vmcnt(8)" ::: "memory");  // tile t landed; t+1 in flight
    } else {
      asm volatile("s_waitcnt vmcnt(0)" ::: "memory");
    }
    __builtin_amdgcn_sched_barrier(0);
    __builtin_amdgcn_s_barrier();
    __builtin_amdgcn_sched_barrier(0);

    #pragma unroll
    for (int kk = 0; kk < 2; ++kk) {
      bf16x8 av[8], bv[4];
      #pragma unroll
      for (int f = 0; f < 8; ++f) {
        const int ra = (wm << 7) + (f << 4) + r16;
        const int sa = ((kk << 2) + ch) ^ (ra & 7);
        av[f] = *(const bf16x8*)&Al[cur][(ra << 6) + (sa << 3)];
      }
      #pragma unroll
      for (int f = 0; f < 4; ++f) {
        const int rb = (wn << 6) + (f << 4) + r16;
        const int sb = ((kk << 2) + ch) ^ (rb & 7);
        bv[f] = *(const bf16x8*)&Bl[cur][(rb << 6) + (sb << 3)];
      }
      __builtin_amdgcn_s_setprio(1);
      #pragma unroll
      for (int fm = 0; fm < 8; ++fm)
        #pragma unroll
        for (int fn = 0; fn < 4; ++fn)
          acc[fm][fn] = __builtin_amdgcn_mfma_f32_16x16x32_bf16(av[fm], bv[fn], acc[fm][fn], 0, 0, 0);
      __builtin_amdgcn_s_setprio(0);
    }
    __builtin_amdgcn_sched_barrier(0);
    __builtin_amdgcn_s_barrier();
    __builtin_amdgcn_sched_barrier(0);
  }

  const int rbase = row0 + (wm << 7) + ((lane >> 4) << 2);
  const int cbase = col0 + (wn << 6) + (lane & 15);
  #pragma unroll
  for (int fm = 0; fm < 8; ++fm)
    #pragma unroll
    for (int fn = 0; fn < 4; ++fn)
      #pragma unroll
      for (int j = 0; j < 4; ++j) {
        const int gr = rbase + (fm << 4) + j;
        const int gc = cbase + (fn << 4);
        C[(size_t)gr * ldc + gc] = acc[fm][fn][j];
      }
}

extern "C" void kernel_launch(void* const* d_in, const int* in_sizes, int n_in,
                              void* d_out, int out_size, void* d_ws, size_t ws_size,
                              hipStream_t stream) {
  (void)in_sizes; (void)n_in; (void)out_size; (void)ws_size;
  const float* v0 = (const float*)d_in[0];
  const float* v1 = (const float*)d_in[1];
  const float* B0 = (const float*)d_in[2];
  const float* q  = (const float*)d_in[3];
  float* out = (float*)d_out;

  size_t off = 0;
  char* base = (char*)d_ws;
  auto alloc = [&](size_t bytes) -> u16* {
    char* r = base + off;
    off += (bytes + 255) & ~(size_t)255;
    return (u16*)r;
  };
  u16* zzT  = alloc((size_t)NBB * LDW * 2);  // 33.6 MB
  u16* Wb   = alloc((size_t)LDW * LDW * 2);  //  8.4 MB
  u16* B0h  = alloc((size_t)NU * NU * 2);
  u16* B0Th = alloc((size_t)NU * NU * 2);
  u16* B0Tl = alloc((size_t)NU * NU * 2);
  u16* Mh   = alloc((size_t)NU * NU * 2);
  u16* Ml   = alloc((size_t)NU * NU * 2);
  u16* S1   = alloc((size_t)NU * NU * 2);
  u16* S2   = alloc((size_t)NU * NU * 2);
  u16* S3   = alloc((size_t)NU * NU * 2);   // total ~59 MB

  // Wbig quadrants: [[ I + (-R)B0^T , -R ], [ Q , P ]],  R = B0 P, Q = P B0^T
  u16* WbTL = Wb;
  u16* WbTR = Wb + NU;
  u16* WbBL = Wb + (size_t)NU * LDW;
  u16* WbBR = Wb + (size_t)NU * LDW + NU;

  const u16* NH = nullptr;

  prep_b0<<<dim3(32, 32), dim3(32, 8), 0, stream>>>(B0, B0h, B0Th, B0Tl);
  build_zzT<<<dim3(NBB / 32, NU / 32), dim3(32, 8), 0, stream>>>(v0, v1, q, zzT);

  // M = 2I + B0^T B0 in split precision (hh + lh + hl) -> Mh + Ml
  gemm_s<4,2,0><<<256, 256, 0, stream>>>(B0Th, B0Tl, B0Th, B0Tl, NU, NU,
                                         NH, NU, 1.f, 0.f, 2.f, Mh, Ml, NU);
  // M2 = M*M -> S1; fused G = C2 I + C3 M + C4 M2 -> S2  (Bt = M, symmetric)
  gemm_s<2,3,1><<<256, 256, 0, stream>>>(Mh, nullptr, Mh, nullptr, NU, NU,
                                         Mh, NU, 1.f, 0.f, 0.f, S1, S2, NU);
  // X0 = M2*G + C1*M + C0*I   (Bt = G, symmetric; deg-4 Chebyshev, e0=0.036)
  gemm_s<2,3,0><<<256, 256, 0, stream>>>(S1, nullptr, S2, nullptr, NU, NU,
                                         Mh, NU, 1.f, C1, C0, S3, nullptr, NU);
  // E = I - M*X0              (split M; Bt = X0, symmetric)
  gemm_s<3,3,0><<<256, 256, 0, stream>>>(Mh, Ml, S3, nullptr, NU, NU,
                                         NH, NU, -1.f, 0.f, 1.f, S1, nullptr, NU);
  // P = X0 + X0*E             (Bt = E, symmetric) -> Wbig BR (ldc = 2048)
  gemm_s<2,3,0><<<256, 256, 0, stream>>>(S3, nullptr, S1, nullptr, NU, NU,
                                         S3, NU, 1.f, 1.f, 0.f, WbBR, nullptr, LDW);
  // -R = -(B0 * P)            (Bt = P, symmetric; read from Wb) -> Wbig TR
  gemm_s<2,3,0><<<256, 256, 0, stream>>>(B0h, nullptr, WbBR, nullptr, NU, LDW,
                                         NH, NU, -1.f, 0.f, 0.f, WbTR, nullptr, LDW);
  // Q = P B0^T = -(-R)^T -> Wbig BL (flip-transpose, no GEMM)
  transpose_f<<<dim3(32, 32), dim3(32, 8), 0, stream>>>(WbTR, LDW, WbBL, LDW, 1);
  // TL = I + (-R)*B0^T        (Bt = B0, gamma = 1) -> Wbig TL
  gemm_s<2,3,0><<<256, 256, 0, stream>>>(WbTR, nullptr, B0h, nullptr, LDW, NU,
                                         NH, NU, 1.f, 0.f, 1.f, WbTL, nullptr, LDW);

  // apply: out = Wbig * zzT^T  (2048 x 8192 x 2048)
  gemm_apply<<<(LDW / 256) * (NBB / 256), 512, 0, stream>>>(
      Wb, zzT, out, LDW, LDW, NBB, LDW, NBB, LDW);
}

// Round 13
// 165.712 us; speedup vs baseline: 1.1045x; 1.0252x over previous
//
#include <hip/hip_runtime.h>
#include <stdint.h>

typedef unsigned short u16;
typedef __bf16 bf16x8 __attribute__((ext_vector_type(8)));
typedef float f32x4 __attribute__((ext_vector_type(4)));
typedef __attribute__((address_space(3))) void as3_void;
typedef __attribute__((address_space(1))) void as1_void;

#define NU   1024
#define NBB  8192
#define LDW  2048

// Degree-4 constrained-Chebyshev init for 1/lambda on [2, 13.8]:
// X0 = C0*I + C1*M + M^2*(C2*I + C3*M + C4*M^2), e0 = 0.0363
#define C0 0.9513167f
#define C1 (-0.3169175f)
#define C2 0.0471891f
#define C3 (-0.00321059f)
#define C4 0.00008127825f

// ---------- bf16 helpers (RNE, bit ops; inputs finite) ----------
__device__ __forceinline__ u16 f2h(float f) {
  union { float f; uint32_t u; } c; c.f = f;
  uint32_t r = (c.u + 0x7fffu + ((c.u >> 16) & 1u)) >> 16;
  return (u16)r;
}
__device__ __forceinline__ float h2f(u16 h) {
  union { uint32_t u; float f; } c; c.u = ((uint32_t)h) << 16;
  return c.f;
}

__device__ __forceinline__ void gload16(const u16* g, u16* l) {
  __builtin_amdgcn_global_load_lds((const as1_void*)g, (as3_void*)l, 16, 0, 0);
}

// ---------- fused prep: blocks [0,1024): B0 -> B0h, B0Th/B0Tl (hi/lo);
// blocks [1024, 9216): zzT[b][i] = z1, zzT[b][i+NU] = z2 (transposed bf16) ----------
__global__ void prep_fused(const float* __restrict__ B0, u16* __restrict__ B0h,
                           u16* __restrict__ B0Th, u16* __restrict__ B0Tl,
                           const float* __restrict__ v0, const float* __restrict__ v1,
                           const float* __restrict__ q, u16* __restrict__ zzT) {
  __shared__ float tf[32][33];
  __shared__ u16 s1[32][33], s2[32][33];
  const int x = threadIdx.x, y0 = threadIdx.y;
  const int b = (int)blockIdx.x;
  if (b < 1024) {
    const int bx = b & 31, by = b >> 5;
    #pragma unroll
    for (int yy = y0; yy < 32; yy += 8) {
      const int r = by * 32 + yy, c = bx * 32 + x;
      const float v = B0[(size_t)r * NU + c];
      tf[yy][x] = v;
      B0h[(size_t)r * NU + c] = f2h(v);
    }
    __syncthreads();
    #pragma unroll
    for (int yy = y0; yy < 32; yy += 8) {
      const int r = bx * 32 + yy, c = by * 32 + x;  // B0T[r][c] = B0[c][r]
      const float v = tf[x][yy];
      const u16 hh = f2h(v);
      B0Th[(size_t)r * NU + c] = hh;
      B0Tl[(size_t)r * NU + c] = f2h(v - h2f(hh));
    }
  } else {
    const int b2 = b - 1024;
    const int bx = b2 & 255, by = b2 >> 8;  // batch tile, unit tile
    #pragma unroll
    for (int yy = y0; yy < 32; yy += 8) {
      const int i = by * 32 + yy;
      const int bb = bx * 32 + x;
      const float a0 = v0[(size_t)i * NBB + bb];
      const float a1 = v1[(size_t)i * NBB + bb];
      s1[yy][x] = f2h(a0 + 0.1f * q[i]);
      s2[yy][x] = f2h(a1 + tanhf(a0));
    }
    __syncthreads();
    #pragma unroll
    for (int yy = y0; yy < 32; yy += 8) {
      const int bb = bx * 32 + yy;
      const int i = by * 32 + x;
      zzT[(size_t)bb * LDW + i]      = s1[x][yy];
      zzT[(size_t)bb * LDW + NU + i] = s2[x][yy];
    }
  }
}

// ---------- small setup GEMM: 64x64 tile, BK={128,256}, 4 waves (2x2,
// wave tile 32x32), PDIST-deep prefetch, issue-early staging, counted vmcnt.
// C = A * Bt^T, 1024^3 shapes.
// NOPS: 2 = A0*B0; 3 = (A0+A1)*B0; 4 = A0B0 + A1B0 + A0B1 (split precision).
// EMODE 0: outH(+outL lo-split) = bf16(alpha*acc + beta*aux + gamma*I).
// EMODE 1: outH = bf16(acc) [M2]; outL = bf16(C4*acc + C3*aux + C2*I) [G].
// EMODE 2: outH[gr][gc] = bf16(alpha*acc); outL[gc][gr] = -outH (fused -Q^T). ----------
template<int NOPS, int PDIST, int BK, int EMODE>
__global__ __launch_bounds__(256, 1)
void gemm_s(const u16* __restrict__ A0, const u16* __restrict__ A1,
            const u16* __restrict__ Bt0, const u16* __restrict__ Bt1,
            int lda, int ldb,
            const u16* __restrict__ aux, int ldaux,
            float alpha, float beta, float gamma,
            u16* __restrict__ outH, u16* __restrict__ outL, int ldc) {
  constexpr int NA = (NOPS >= 3) ? 2 : 1;
  constexpr int NB2 = (NOPS == 4) ? 2 : 1;
  constexpr int RA = (64 * BK) / (256 * 8);   // staging rounds per op buffer
  constexpr int LOADS = RA * (NA + NB2);
  constexpr int STEADY = LOADS * (PDIST - 1);
  constexpr int SEGS = BK / 8;                // 8-elem segs per row
  __shared__ u16 Al[PDIST][NA][64 * BK];
  __shared__ u16 Bl[PDIST][NB2][64 * BK];

  int wg = (int)blockIdx.x;
  { wg = (wg & 7) * 32 + (wg >> 3); }  // XCD swizzle, grid 256
  const int tm = wg & 15, tn = wg >> 4;
  const int row0 = tm << 6, col0 = tn << 6;

  const int tid = threadIdx.x;
  const int lane = tid & 63, wid = tid >> 6;
  const int wm = wid >> 1, wn = wid & 1;
  const int r16 = lane & 15, ch = lane >> 4;

  f32x4 acc[2][2] = {};

  auto stageAll = [&](int k0, int buf) {
    #pragma unroll
    for (int h = 0; h < RA; ++h) {
      const int L = tid + (h << 8);
      const int row = L / SEGS;
      const int ss = (L & (SEGS - 1)) ^ (row & 7);
      const size_t go = (size_t)(row0 + row) * lda + (size_t)(k0 + (ss << 3));
      gload16(A0 + go, &Al[buf][0][(L & ~63) << 3]);
      if constexpr (NA == 2) gload16(A1 + go, &Al[buf][1][(L & ~63) << 3]);
    }
    #pragma unroll
    for (int h = 0; h < RA; ++h) {
      const int L = tid + (h << 8);
      const int row = L / SEGS;
      const int ss = (L & (SEGS - 1)) ^ (row & 7);
      const size_t go = (size_t)(col0 + row) * ldb + (size_t)(k0 + (ss << 3));
      gload16(Bt0 + go, &Bl[buf][0][(L & ~63) << 3]);
      if constexpr (NB2 == 2) gload16(Bt1 + go, &Bl[buf][1][(L & ~63) << 3]);
    }
  };

  const int nK = 1024 / BK;
  stageAll(0, 0);
  if constexpr (PDIST == 3) stageAll(BK, 1);

  int cur = 0;
  for (int t = 0; t < nK; ++t) {
    int bs = cur + (PDIST - 1); if (bs >= PDIST) bs -= PDIST;
    if (t + PDIST - 1 < nK) {
      stageAll((t + PDIST - 1) * BK, bs);
      if constexpr (STEADY == 8)       asm volatile("s_waitcnt vmcnt(8)" ::: "memory");
      else if constexpr (STEADY == 12) asm volatile("s_waitcnt vmcnt(12)" ::: "memory");
      else if constexpr (STEADY == 16) asm volatile("s_waitcnt vmcnt(16)" ::: "memory");
      else if constexpr (STEADY == 24) asm volatile("s_waitcnt vmcnt(24)" ::: "memory");
      else                             asm volatile("s_waitcnt vmcnt(32)" ::: "memory");
    } else if (PDIST == 3 && t + 1 < nK) {
      if constexpr (LOADS == 8)       asm volatile("s_waitcnt vmcnt(8)" ::: "memory");
      else if constexpr (LOADS == 12) asm volatile("s_waitcnt vmcnt(12)" ::: "memory");
      else                            asm volatile("s_waitcnt vmcnt(16)" ::: "memory");
    } else {
      asm volatile("s_waitcnt vmcnt(0)" ::: "memory");
    }
    __builtin_amdgcn_sched_barrier(0);
    __builtin_amdgcn_s_barrier();
    __builtin_amdgcn_sched_barrier(0);

    #pragma unroll
    for (int kk = 0; kk < BK / 32; ++kk) {
      bf16x8 av[2], bv[2], av1[2], bv1[2];
      #pragma unroll
      for (int f = 0; f < 2; ++f) {
        const int ra = (wm << 5) + (f << 4) + r16;
        const int sa = ((kk << 2) + ch) ^ (ra & 7);
        av[f] = *(const bf16x8*)&Al[cur][0][ra * BK + (sa << 3)];
        if constexpr (NA == 2)
          av1[f] = *(const bf16x8*)&Al[cur][1][ra * BK + (sa << 3)];
        const int rb = (wn << 5) + (f << 4) + r16;
        const int sb = ((kk << 2) + ch) ^ (rb & 7);
        bv[f] = *(const bf16x8*)&Bl[cur][0][rb * BK + (sb << 3)];
        if constexpr (NB2 == 2)
          bv1[f] = *(const bf16x8*)&Bl[cur][1][rb * BK + (sb << 3)];
      }
      __builtin_amdgcn_s_setprio(1);
      #pragma unroll
      for (int fm = 0; fm < 2; ++fm)
        #pragma unroll
        for (int fn = 0; fn < 2; ++fn)
          acc[fm][fn] = __builtin_amdgcn_mfma_f32_16x16x32_bf16(av[fm], bv[fn], acc[fm][fn], 0, 0, 0);
      if constexpr (NA == 2) {
        #pragma unroll
        for (int fm = 0; fm < 2; ++fm)
          #pragma unroll
          for (int fn = 0; fn < 2; ++fn)
            acc[fm][fn] = __builtin_amdgcn_mfma_f32_16x16x32_bf16(av1[fm], bv[fn], acc[fm][fn], 0, 0, 0);
      }
      if constexpr (NB2 == 2) {
        #pragma unroll
        for (int fm = 0; fm < 2; ++fm)
          #pragma unroll
          for (int fn = 0; fn < 2; ++fn)
            acc[fm][fn] = __builtin_amdgcn_mfma_f32_16x16x32_bf16(av[fm], bv1[fn], acc[fm][fn], 0, 0, 0);
      }
      __builtin_amdgcn_s_setprio(0);
    }
    __builtin_amdgcn_sched_barrier(0);
    __builtin_amdgcn_s_barrier();
    __builtin_amdgcn_sched_barrier(0);
    ++cur; if (cur == PDIST) cur = 0;
  }

  // epilogue: C/D layout: col = lane&15, row = (lane>>4)*4 + j
  const int rbase = row0 + (wm << 5) + ((lane >> 4) << 2);
  const int cbase = col0 + (wn << 5) + (lane & 15);
  #pragma unroll
  for (int fm = 0; fm < 2; ++fm)
    #pragma unroll
    for (int fn = 0; fn < 2; ++fn)
      #pragma unroll
      for (int j = 0; j < 4; ++j) {
        const int gr = rbase + (fm << 4) + j;
        const int gc = cbase + (fn << 4);
        const float a = acc[fm][fn][j];
        if constexpr (EMODE == 0) {
          float v = alpha * a;
          if (aux) v += beta * h2f(aux[(size_t)gr * ldaux + gc]);
          if (gamma != 0.f && gr == gc) v += gamma;
          const u16 hh = f2h(v);
          outH[(size_t)gr * ldc + gc] = hh;
          if (outL) outL[(size_t)gr * ldc + gc] = f2h(v - h2f(hh));
        } else if constexpr (EMODE == 1) {
          // fused: outH = M2, outL = G = C2*I + C3*M + C4*M2 (from fp32 acc)
          outH[(size_t)gr * ldc + gc] = f2h(a);
          float g = C4 * a + C3 * h2f(aux[(size_t)gr * ldaux + gc]);
          if (gr == gc) g += C2;
          outL[(size_t)gr * ldc + gc] = f2h(g);
        } else {
          // R stage: outH = bf16(alpha*acc) = -R; outL[gc][gr] = -outH = Q
          const u16 hh = f2h(alpha * a);
          outH[(size_t)gr * ldc + gc] = hh;
          outL[(size_t)gc * ldc + gr] = (u16)(hh ^ 0x8000u);
        }
      }
}

// ---------- apply GEMM (R3/R7/R9/R11/R12-verified, 80-81.5 us): 256x256 tile,
// BK=64, 8 waves (2x4), dbuf LDS, issue-early staging + counted vmcnt(8),
// raw barriers. C (fp32) = A (bf16 [M][K]) * Bt^T (bf16 [N][K]) ----------
__global__ __launch_bounds__(512, 2)
void gemm_apply(const u16* __restrict__ A, const u16* __restrict__ Bt,
                float* __restrict__ C, int lda, int ldb, int ldc,
                int M, int N, int K) {
  __shared__ u16 Al[2][256 * 64];
  __shared__ u16 Bl[2][256 * 64];

  const int nTm = M >> 8, nTn = N >> 8;
  const int nwg = nTm * nTn;
  int wg = (int)blockIdx.x;
  { const int c = nwg >> 3; wg = (wg & 7) * c + (wg >> 3); }  // XCD swizzle
  const int tm = wg % nTm, tn = wg / nTm;                     // tn-major
  const int row0 = tm << 8, col0 = tn << 8;

  const int tid = threadIdx.x;
  const int lane = tid & 63, wid = tid >> 6;
  const int wm = wid >> 2, wn = wid & 3;   // wave tile 128x64
  const int r16 = lane & 15, ch = lane >> 4;

  f32x4 acc[8][4] = {};

  auto stage = [&](const u16* __restrict__ G, int gld, int grow0, int k0, u16* lb) {
    #pragma unroll
    for (int h = 0; h < 4; ++h) {
      const int L = tid + (h << 9);
      const int row = L >> 3, seg = L & 7;
      const int ss = seg ^ (row & 7);
      gload16(G + (size_t)(grow0 + row) * gld + (size_t)(k0 + (ss << 3)),
              lb + ((L & ~63) << 3));
    }
  };

  const int nK = K >> 6;
  stage(A, lda, row0, 0, &Al[0][0]);
  stage(Bt, ldb, col0, 0, &Bl[0][0]);

  for (int t = 0; t < nK; ++t) {
    const int cur = t & 1;
    if (t + 1 < nK) {
      stage(A, lda, row0, (t + 1) << 6, &Al[cur ^ 1][0]);
      stage(Bt, ldb, col0, (t + 1) << 6, &Bl[cur ^ 1][0]);
      asm volatile("s_waitcnt vmcnt(8)" ::: "memory");  // tile t landed; t+1 in flight
    } else {
      asm volatile("s_waitcnt vmcnt(0)" ::: "memory");
    }
    __builtin_amdgcn_sched_barrier(0);
    __builtin_amdgcn_s_barrier();
    __builtin_amdgcn_sched_barrier(0);

    #pragma unroll
    for (int kk = 0; kk < 2; ++kk) {
      bf16x8 av[8], bv[4];
      #pragma unroll
      for (int f = 0; f < 8; ++f) {
        const int ra = (wm << 7) + (f << 4) + r16;
        const int sa = ((kk << 2) + ch) ^ (ra & 7);
        av[f] = *(const bf16x8*)&Al[cur][(ra << 6) + (sa << 3)];
      }
      #pragma unroll
      for (int f = 0; f < 4; ++f) {
        const int rb = (wn << 6) + (f << 4) + r16;
        const int sb = ((kk << 2) + ch) ^ (rb & 7);
        bv[f] = *(const bf16x8*)&Bl[cur][(rb << 6) + (sb << 3)];
      }
      __builtin_amdgcn_s_setprio(1);
      #pragma unroll
      for (int fm = 0; fm < 8; ++fm)
        #pragma unroll
        for (int fn = 0; fn < 4; ++fn)
          acc[fm][fn] = __builtin_amdgcn_mfma_f32_16x16x32_bf16(av[fm], bv[fn], acc[fm][fn], 0, 0, 0);
      __builtin_amdgcn_s_setprio(0);
    }
    __builtin_amdgcn_sched_barrier(0);
    __builtin_amdgcn_s_barrier();
    __builtin_amdgcn_sched_barrier(0);
  }

  const int rbase = row0 + (wm << 7) + ((lane >> 4) << 2);
  const int cbase = col0 + (wn << 6) + (lane & 15);
  #pragma unroll
  for (int fm = 0; fm < 8; ++fm)
    #pragma unroll
    for (int fn = 0; fn < 4; ++fn)
      #pragma unroll
      for (int j = 0; j < 4; ++j) {
        const int gr = rbase + (fm << 4) + j;
        const int gc = cbase + (fn << 4);
        C[(size_t)gr * ldc + gc] = acc[fm][fn][j];
      }
}

extern "C" void kernel_launch(void* const* d_in, const int* in_sizes, int n_in,
                              void* d_out, int out_size, void* d_ws, size_t ws_size,
                              hipStream_t stream) {
  (void)in_sizes; (void)n_in; (void)out_size; (void)ws_size;
  const float* v0 = (const float*)d_in[0];
  const float* v1 = (const float*)d_in[1];
  const float* B0 = (const float*)d_in[2];
  const float* q  = (const float*)d_in[3];
  float* out = (float*)d_out;

  size_t off = 0;
  char* base = (char*)d_ws;
  auto alloc = [&](size_t bytes) -> u16* {
    char* r = base + off;
    off += (bytes + 255) & ~(size_t)255;
    return (u16*)r;
  };
  u16* zzT  = alloc((size_t)NBB * LDW * 2);  // 33.6 MB
  u16* Wb   = alloc((size_t)LDW * LDW * 2);  //  8.4 MB
  u16* B0h  = alloc((size_t)NU * NU * 2);
  u16* B0Th = alloc((size_t)NU * NU * 2);
  u16* B0Tl = alloc((size_t)NU * NU * 2);
  u16* Mh   = alloc((size_t)NU * NU * 2);
  u16* Ml   = alloc((size_t)NU * NU * 2);
  u16* S1   = alloc((size_t)NU * NU * 2);
  u16* S2   = alloc((size_t)NU * NU * 2);
  u16* S3   = alloc((size_t)NU * NU * 2);   // total ~59 MB

  // Wbig quadrants: [[ I + (-R)B0^T , -R ], [ Q , P ]],  R = B0 P, Q = P B0^T
  u16* WbTL = Wb;
  u16* WbTR = Wb + NU;
  u16* WbBL = Wb + (size_t)NU * LDW;
  u16* WbBR = Wb + (size_t)NU * LDW + NU;

  const u16* NH = nullptr;

  // fused prep_b0 + build_zzT (blocks [0,1024) prep, [1024,9216) zzT)
  prep_fused<<<1024 + NBB / 32 * (NU / 32), dim3(32, 8), 0, stream>>>(
      B0, B0h, B0Th, B0Tl, v0, v1, q, zzT);

  // M = 2I + B0^T B0 in split precision (hh + lh + hl) -> Mh + Ml
  gemm_s<4,2,128,0><<<256, 256, 0, stream>>>(B0Th, B0Tl, B0Th, B0Tl, NU, NU,
                                             NH, NU, 1.f, 0.f, 2.f, Mh, Ml, NU);
  // M2 = M*M -> S1; fused G = C2 I + C3 M + C4 M2 -> S2  (Bt = M, symmetric)
  gemm_s<2,2,256,1><<<256, 256, 0, stream>>>(Mh, nullptr, Mh, nullptr, NU, NU,
                                             Mh, NU, 1.f, 0.f, 0.f, S1, S2, NU);
  // X0 = M2*G + C1*M + C0*I   (Bt = G, symmetric; deg-4 Chebyshev, e0=0.036)
  gemm_s<2,2,256,0><<<256, 256, 0, stream>>>(S1, nullptr, S2, nullptr, NU, NU,
                                             Mh, NU, 1.f, C1, C0, S3, nullptr, NU);
  // E = I - M*X0              (split M; Bt = X0, symmetric)
  gemm_s<3,3,128,0><<<256, 256, 0, stream>>>(Mh, Ml, S3, nullptr, NU, NU,
                                             NH, NU, -1.f, 0.f, 1.f, S1, nullptr, NU);
  // P = X0 + X0*E             (Bt = E, symmetric) -> Wbig BR (ldc = 2048)
  gemm_s<2,2,256,0><<<256, 256, 0, stream>>>(S3, nullptr, S1, nullptr, NU, NU,
                                             S3, NU, 1.f, 1.f, 0.f, WbBR, nullptr, LDW);
  // -R = -(B0 * P) -> Wbig TR; fused companion Q = -(-R)^T -> Wbig BL
  gemm_s<2,2,256,2><<<256, 256, 0, stream>>>(B0h, nullptr, WbBR, nullptr, NU, LDW,
                                             NH, NU, -1.f, 0.f, 0.f, WbTR, WbBL, LDW);
  // TL = I + (-R)*B0^T        (Bt = B0, gamma = 1) -> Wbig TL
  gemm_s<2,2,256,0><<<256, 256, 0, stream>>>(WbTR, nullptr, B0h, nullptr, LDW, NU,
                                             NH, NU, 1.f, 0.f, 1.f, WbTL, nullptr, LDW);

  // apply: out = Wbig * zzT^T  (2048 x 8192 x 2048)
  gemm_apply<<<(LDW / 256) * (NBB / 256), 512, 0, stream>>>(
      Wb, zzT, out, LDW, LDW, NBB, LDW, NBB, LDW);
}